// Round 3
// baseline (664.458 us; speedup 1.0000x reference)
//
#include <hip/hip_runtime.h>
#include <cmath>

// Problem constants (from reference setup_inputs)
constexpr int B = 16, T = 2048, D = 2048, C = 100;
#define EPS_F 1e-7f

// native clang vector type — required by __builtin_nontemporal_load
typedef float v4f __attribute__((ext_vector_type(4)));

// ---------------------------------------------------------------------------
// Kernel 1: column sum over T for BOTH feat tensors in one launch.
// z in [0,2B): z<B -> feat_act batch z ; z>=B -> feat_bkg batch z-B.
// out laid out [2B, D]. 16B nontemporal loads, compile-time ROWS for unroll.
// grid = (D/1024, T/ROWS, 2B), block = 256
// ---------------------------------------------------------------------------
template <int ROWS>
__global__ __launch_bounds__(256) void colsum_kernel(
        const float* __restrict__ fa, const float* __restrict__ fb,
        float* __restrict__ out) {
    const int z = blockIdx.z;
    const float* feat = (z < B) ? fa : fb;
    const int b = (z < B) ? z : z - B;
    const int d0 = (blockIdx.x * 256 + threadIdx.x) * 4;
    const int t0 = blockIdx.y * ROWS;
    const float* base = feat + ((size_t)b * T + t0) * D + d0;
    v4f acc = (v4f)(0.f);
#pragma unroll 8
    for (int t = 0; t < ROWS; ++t) {
        v4f v = __builtin_nontemporal_load(
            reinterpret_cast<const v4f*>(base + (size_t)t * D));
        acc += v;
    }
    float* o = out + (size_t)z * D + d0;
    atomicAdd(o + 0, acc.x);
    atomicAdd(o + 1, acc.y);
    atomicAdd(o + 2, acc.z);
    atomicAdd(o + 3, acc.w);
}

// ---------------------------------------------------------------------------
// Kernel 2: per-(b,c) stats for loss_sup, 16B-vectorized over c.
// thread j = tid&31 (j<25 active) owns classes 4j..4j+3; r = tid>>5 is the
// row slot (8 rows in flight per block), rows step by 8 inside the chunk.
// grid = (T/ROWS, B), block = 256
// ---------------------------------------------------------------------------
template <int ROWS>
__global__ __launch_bounds__(256) void sup_kernel(
        const float* __restrict__ gt, const float* __restrict__ sup,
        float* __restrict__ sumsq, float* __restrict__ cnt) {
    const int b = blockIdx.y;
    const int j = threadIdx.x & 31;
    const int r = threadIdx.x >> 5;
    if (j >= C / 4) return;
    const int t0 = blockIdx.x * ROWS + r;
    size_t base = ((size_t)b * T + t0) * C + 4 * j;
    v4f acc = (v4f)(0.f);
    v4f pc  = (v4f)(0.f);
#pragma unroll
    for (int t = 0; t < ROWS; t += 8) {
        v4f g = __builtin_nontemporal_load(
            reinterpret_cast<const v4f*>(gt  + base + (size_t)t * C));
        v4f s = __builtin_nontemporal_load(
            reinterpret_cast<const v4f*>(sup + base + (size_t)t * C));
        float m, d;
        m = (g.x > 0.5f) ? 1.f : 0.f; d = s.x - m; acc.x += d * d; pc.x += m;
        m = (g.y > 0.5f) ? 1.f : 0.f; d = s.y - m; acc.y += d * d; pc.y += m;
        m = (g.z > 0.5f) ? 1.f : 0.f; d = s.z - m; acc.z += d * d; pc.z += m;
        m = (g.w > 0.5f) ? 1.f : 0.f; d = s.w - m; acc.w += d * d; pc.w += m;
    }
    float* sq = sumsq + b * C + 4 * j;
    float* ct = cnt   + b * C + 4 * j;
    atomicAdd(sq + 0, acc.x); atomicAdd(sq + 1, acc.y);
    atomicAdd(sq + 2, acc.z); atomicAdd(sq + 3, acc.w);
    atomicAdd(ct + 0, pc.x);  atomicAdd(ct + 1, pc.y);
    atomicAdd(ct + 2, pc.z);  atomicAdd(ct + 3, pc.w);
}

// ---------------------------------------------------------------------------
// Kernel 3: sum of squared differences (cas_s - cas_t)^2 over all elements.
// ---------------------------------------------------------------------------
__global__ __launch_bounds__(256) void st_kernel(
        const float* __restrict__ s, const float* __restrict__ t,
        float* __restrict__ acc, int n4) {
    int idx = blockIdx.x * blockDim.x + threadIdx.x;
    int stride = gridDim.x * blockDim.x;
    float local = 0.f;
    for (int i = idx; i < n4; i += stride) {
        v4f a  = __builtin_nontemporal_load(
            reinterpret_cast<const v4f*>(s) + i);
        v4f b4 = __builtin_nontemporal_load(
            reinterpret_cast<const v4f*>(t) + i);
        v4f d = a - b4;
        local += d.x * d.x + d.y * d.y + d.z * d.z + d.w * d.w;
    }
    for (int off = 32; off; off >>= 1) local += __shfl_down(local, off, 64);
    __shared__ float wsum[4];
    int lane = threadIdx.x & 63, wv = threadIdx.x >> 6;
    if (lane == 0) wsum[wv] = local;
    __syncthreads();
    if (threadIdx.x == 0)
        atomicAdd(acc, wsum[0] + wsum[1] + wsum[2] + wsum[3]);
}

// ---------------------------------------------------------------------------
// Kernel 4: final single-block finishing. Shuffle-based block reduce.
// ---------------------------------------------------------------------------
__device__ __forceinline__ float block_reduce(float v, float* s4) {
    for (int off = 32; off; off >>= 1) v += __shfl_down(v, off, 64);
    int lane = threadIdx.x & 63, wv = threadIdx.x >> 6;
    __syncthreads();               // protect s4 against previous use
    if (lane == 0) s4[wv] = v;
    __syncthreads();
    return s4[0] + s4[1] + s4[2] + s4[3];
}

__global__ __launch_bounds__(256) void final_kernel(
        const float* __restrict__ score_act,
        const float* __restrict__ score_bkg,
        const float* __restrict__ label,
        const float* __restrict__ colsum,      // [2B, D]: act rows 0..B-1
        const float* __restrict__ sup_sumsq,
        const float* __restrict__ sup_cnt,
        const float* __restrict__ st_acc,
        float* __restrict__ out) {
    __shared__ float s4[4];
    __shared__ float rowsum[B];
    __shared__ float an[B], bn[B];
    const int tid = threadIdx.x;
    const int N = B * C;

    if (tid < B) rowsum[tid] = 0.f;
    __syncthreads();
    for (int i = tid; i < N; i += 256) atomicAdd(&rowsum[i / C], label[i]);
    __syncthreads();

    // loss_cls: BCE(score_act, label / rowsum)
    float lc = 0.f;
    for (int i = tid; i < N; i += 256) {
        float tgt = label[i] / rowsum[i / C];
        float p = fminf(fmaxf(score_act[i], EPS_F), 1.f - EPS_F);
        lc -= tgt * logf(p) + (1.f - tgt) * log1pf(-p);
    }
    float loss_cls = block_reduce(lc, s4) / (float)N;

    // loss_be: BCE(score_bkg, 1/C)
    float lb = 0.f;
    const float u = 1.f / (float)C;
    for (int i = tid; i < N; i += 256) {
        float p = fminf(fmaxf(score_bkg[i], EPS_F), 1.f - EPS_F);
        lb -= u * logf(p) + (1.f - u) * log1pf(-p);
    }
    float loss_be = block_reduce(lb, s4) / (float)N;

    // norms of mean features (float4 over D)
    const float invT = 1.f / (float)T;
    const v4f* cs4 = reinterpret_cast<const v4f*>(colsum);
    for (int b = 0; b < B; ++b) {
        float la = 0.f, lg = 0.f;
        for (int i = tid; i < D / 4; i += 256) {
            v4f va = cs4[(size_t)b * (D / 4) + i];
            v4f vb = cs4[(size_t)(b + B) * (D / 4) + i];
            la += (va.x * va.x + va.y * va.y + va.z * va.z + va.w * va.w) * invT * invT;
            lg += (vb.x * vb.x + vb.y * vb.y + vb.z * vb.z + vb.w * vb.w) * invT * invT;
        }
        float sa = block_reduce(la, s4);
        float sb = block_reduce(lg, s4);
        if (tid == 0) { an[b] = sqrtf(sa); bn[b] = sqrtf(sb); }
    }
    __syncthreads();

    // loss_sup
    float ss = 0.f, sc = 0.f;
    for (int i = tid; i < N; i += 256) {
        if (sup_cnt[i] > 0.f) { ss += sqrtf(sup_sumsq[i]); sc += 1.f; }
    }
    float sup_sum   = block_reduce(ss, s4);
    float sup_count = block_reduce(sc, s4);

    if (tid == 0) {
        float loss_um = 0.f;
        for (int b = 0; b < B; ++b) {
            float la = fmaxf(100.f - an[b], 0.f);
            float v = la + bn[b];
            loss_um += v * v;
        }
        loss_um /= (float)B;
        float loss_sup = sup_sum / fmaxf(sup_count, 1.f);
        float loss_st = *st_acc / (float)((size_t)B * T * C);
        float total = loss_cls + 0.0005f * loss_um + 1.0f * loss_be
                    + 1.0f * loss_sup + 1.0f * loss_st;
        out[0] = total;
        out[1] = loss_cls;
        out[2] = loss_be;
        out[3] = loss_um;
        out[4] = loss_sup;
        out[5] = loss_st;
    }
}

// ---------------------------------------------------------------------------
extern "C" void kernel_launch(void* const* d_in, const int* in_sizes, int n_in,
                              void* d_out, int out_size, void* d_ws, size_t ws_size,
                              hipStream_t stream) {
    const float* score_act = (const float*)d_in[0];
    const float* score_bkg = (const float*)d_in[1];
    const float* feat_act  = (const float*)d_in[2];
    const float* feat_bkg  = (const float*)d_in[3];
    const float* label     = (const float*)d_in[4];
    const float* gt        = (const float*)d_in[5];
    const float* sup_cas   = (const float*)d_in[6];
    const float* cas_s     = (const float*)d_in[7];
    const float* cas_t     = (const float*)d_in[8];
    float* out = (float*)d_out;
    float* ws  = (float*)d_ws;

    // workspace (floats): colsum[2B*D] | sup_sumsq[B*C] | sup_cnt[B*C] | st_acc[1]
    float* colsum    = ws;
    float* sup_sumsq = ws + (size_t)2 * B * D;
    float* sup_cnt   = sup_sumsq + B * C;
    float* st_acc    = sup_cnt + B * C;
    size_t ws_needed = ((size_t)2 * B * D + 2 * B * C + 1) * sizeof(float);

    (void)hipMemsetAsync(d_ws, 0, ws_needed, stream);

    {
        constexpr int ROWS = 64;
        dim3 grid(D / (256 * 4), T / ROWS, 2 * B);   // (2, 32, 32) = 2048 blocks
        colsum_kernel<ROWS><<<grid, 256, 0, stream>>>(feat_act, feat_bkg, colsum);
    }
    {
        constexpr int ROWS = 64;
        dim3 grid(T / ROWS, B);                      // (32, 16) = 512 blocks
        sup_kernel<ROWS><<<grid, 256, 0, stream>>>(gt, sup_cas, sup_sumsq, sup_cnt);
    }
    {
        int n4 = (B * T * C) / 4;                    // 819200
        st_kernel<<<1024, 256, 0, stream>>>(cas_s, cas_t, st_acc, n4);
    }
    final_kernel<<<1, 256, 0, stream>>>(score_act, score_bkg, label,
                                        colsum, sup_sumsq, sup_cnt, st_acc, out);
}